// Round 17
// baseline (121.491 us; speedup 1.0000x reference)
//
#include <hip/hip_runtime.h>
#include <hip/hip_bf16.h>

// UnifiedAttention: x->QKV gemm -> causal MHA (H=16,D=64) -> proj gemm
// B=2, N=2048, C=1024. bf16 MFMA with fp32 accum throughout.

typedef __bf16 bf16x8 __attribute__((ext_vector_type(8)));
typedef __bf16 bf16x4 __attribute__((ext_vector_type(4)));
typedef __bf16 bf16x2 __attribute__((ext_vector_type(2)));
typedef float  f32x4  __attribute__((ext_vector_type(4)));
typedef float  f32x16 __attribute__((ext_vector_type(16)));
typedef int    i32x4  __attribute__((ext_vector_type(4)));

#define MFMA16(a, b, c) __builtin_amdgcn_mfma_f32_16x16x32_bf16((a), (b), (c), 0, 0, 0)

__device__ __forceinline__ void async_copy16(const __bf16* g, __bf16* l) {
    __builtin_amdgcn_global_load_lds(
        (const __attribute__((address_space(1))) void*)g,
        (__attribute__((address_space(3))) void*)l,
        16, 0, 0);
}

__device__ __forceinline__ unsigned packbf(float a, float b) {
    union { bf16x2 v; unsigned u; } un;
    un.v[0] = (__bf16)a; un.v[1] = (__bf16)b;
    return un.u;
}

// -------- merged prep: fp32->bf16 conversions (blocks 0..8191) + mask reduce ------
__global__ void prep_k(const float* __restrict__ x, __bf16* __restrict__ xb,
                       const float* __restrict__ qkvw, __bf16* __restrict__ wqkv,
                       const float* __restrict__ projw, __bf16* __restrict__ wproj,
                       const int* __restrict__ mask, int* __restrict__ mflag)
{
    if (blockIdx.x < 8192) {
        const int i = blockIdx.x * 256 + threadIdx.x;   // quad index
        const float* src; __bf16* dst; int j;
        if (i < 1048576)            { src = x;     dst = xb;    j = i; }
        else if (i < 1835008)       { src = qkvw;  dst = wqkv;  j = i - 1048576; }
        else                        { src = projw; dst = wproj; j = i - 1835008; }
        float4 v = reinterpret_cast<const float4*>(src)[j];
        bf16x4 o;
        o[0] = (__bf16)v.x; o[1] = (__bf16)v.y; o[2] = (__bf16)v.z; o[3] = (__bf16)v.w;
        reinterpret_cast<bf16x4*>(dst)[j] = o;
    } else {
        __shared__ int ok;
        const int t = threadIdx.x;
        if (t == 0) ok = 1;
        __syncthreads();
        const int bb = blockIdx.x - 8192;
        const int jt = bb & 31;
        const int it = (bb >> 5) & 31;
        const int b  = bb >> 10;
        bool all1 = true;
#pragma unroll
        for (int c = 0; c < 4; ++c) {
            const int row = c * 16 + (t >> 4);
            const int col = (t & 15) * 4;
            const int4 v = *reinterpret_cast<const int4*>(
                &mask[((size_t)(b * 2048 + it * 64 + row)) * 2048 + jt * 64 + col]);
            all1 = all1 && v.x && v.y && v.z && v.w;
        }
        if (!all1) ok = 0;
        __syncthreads();
        if (t == 0) mflag[(b * 32 + it) * 32 + jt] = ok;
    }
}

// ====== 6-phase 256x192 QKV GEMM (T1+T2+T3+T4+T5), K=1024, grid 256 = 1/CU ======
#define BAR() asm volatile("s_barrier" ::: "memory")
#define VM2() asm volatile("s_waitcnt vmcnt(2)" ::: "memory")
#define VM6() asm volatile("s_waitcnt vmcnt(6)" ::: "memory")

__global__ __launch_bounds__(512, 2) void gemm_qkv8_k(
    const __bf16* __restrict__ A, const __bf16* __restrict__ Bm,
    const float* __restrict__ bias,
    __bf16* __restrict__ qg, __bf16* __restrict__ kg, __bf16* __restrict__ vtg)
{
    __shared__ __align__(16) __bf16 As[2][16384];   // [buf][256 rows x 64]
    __shared__ __align__(16) __bf16 Bs[2][12288];   // [buf][192 rows x 64]

    const int t = threadIdx.x;
    const int lane = t & 63;
    const int w = t >> 6;
    const int wr = w >> 2, wc = w & 3;
    const int li = lane & 15, g = lane >> 4;

    // XCD-aware bijective swizzle (grid=256, 256%8==0, 32 blocks per XCD)
    const int bid = (blockIdx.x & 7) * 32 + (blockIdx.x >> 3);
    const int m0 = (bid >> 4) << 8;     // 16 m-tiles of 256
    const int n0 = (bid & 15) * 192;    // 16 n-tiles of 192

    const int srow = t >> 3;            // 0..63
    const int scol = ((t & 7) ^ (srow & 7)) << 3;
    const __bf16* pA = A  + (size_t)(m0 + srow) * 1024 + scol;
    const __bf16* pB = Bm + (size_t)(n0 + srow) * 1024 + scol;
    __bf16* dA = &As[0][0] + t * 8;
    __bf16* dB = &Bs[0][0] + t * 8;

#define STAGE_A(BB, T, HH) do {                                                   \
    const size_t ro_ = (size_t)((HH) * 128) * 1024 + (size_t)(T) * 64;            \
    async_copy16(pA + ro_,         dA + (BB) * 16384 + (HH) * 8192);              \
    async_copy16(pA + ro_ + 65536, dA + (BB) * 16384 + (HH) * 8192 + 4096);       \
  } while (0)
#define STAGE_B(BB, T, HH) do {                                                   \
    const size_t ro_ = (size_t)((HH) * 64) * 1024 + (size_t)(T) * 64;             \
    async_copy16(pB + ro_, dB + (BB) * 12288 + (HH) * 4096);                      \
  } while (0)

    const int aoff0 = ((0 + g) ^ (li & 7)) << 3;
    const int aoff1 = ((4 + g) ^ (li & 7)) << 3;
    const int abase = (wr * 128 + li) * 64;
    const int bbase = (wc * 48 + li) * 64;

    f32x4 acc[8][3] = {};
    bf16x8 a[4][2], b[3][2];

#define READ_A(BB, MH) do { _Pragma("unroll")                                     \
    for (int mi2 = 0; mi2 < 4; ++mi2) {                                           \
      const __bf16* p_ = &As[BB][abase + ((MH) * 4 + mi2) * 1024];                \
      a[mi2][0] = *reinterpret_cast<const bf16x8*>(p_ + aoff0);                   \
      a[mi2][1] = *reinterpret_cast<const bf16x8*>(p_ + aoff1); } } while (0)
#define READ_B(BB, NH) do {                                                       \
      const __bf16* p_ = &Bs[BB][bbase + (NH) * 1024];                            \
      b[NH][0] = *reinterpret_cast<const bf16x8*>(p_ + aoff0);                    \
      b[NH][1] = *reinterpret_cast<const bf16x8*>(p_ + aoff1); } while (0)
#define MFMA_QUAD(MH, NH) do {                                                    \
    __builtin_amdgcn_s_setprio(1);                                                \
    _Pragma("unroll") for (int mi2 = 0; mi2 < 4; ++mi2) {                         \
      f32x4 c_ = acc[(MH) * 4 + mi2][NH];                                         \
      c_ = MFMA16(a[mi2][0], b[NH][0], c_);                                       \
      c_ = MFMA16(a[mi2][1], b[NH][1], c_);                                       \
      acc[(MH) * 4 + mi2][NH] = c_; }                                             \
    __builtin_amdgcn_s_setprio(0); } while (0)

#define KTILE(BB, T) do {                                                         \
    const int Tn_  = ((T) + 1 < 16) ? (T) + 1 : 15;                               \
    const int Tn2_ = ((T) + 2 < 16) ? (T) + 2 : 15;                               \
    STAGE_A((BB) ^ 1, Tn_, 1);                                                    \
    READ_A(BB, 0); READ_B(BB, 0);                                                 \
    BAR(); MFMA_QUAD(0, 0); BAR();                                                \
    STAGE_B((BB) ^ 1, Tn_, 0);                                                    \
    READ_B(BB, 1);                                                                \
    BAR(); MFMA_QUAD(0, 1); BAR();                                                \
    STAGE_B((BB) ^ 1, Tn_, 1);                                                    \
    READ_B(BB, 2);                                                                \
    BAR(); MFMA_QUAD(0, 2); BAR();                                                \
    STAGE_B((BB) ^ 1, Tn_, 2);                                                    \
    READ_A(BB, 1);                                                                \
    BAR(); MFMA_QUAD(1, 0); BAR();                                                \
    STAGE_A((BB), Tn2_, 0);                                                       \
    BAR(); MFMA_QUAD(1, 1); BAR();                                                \
    VM2();                                                                        \
    BAR(); MFMA_QUAD(1, 2); BAR();                                                \
  } while (0)

    STAGE_A(0, 0, 0); STAGE_A(0, 0, 1);
    STAGE_B(0, 0, 0); STAGE_B(0, 0, 1); STAGE_B(0, 0, 2);
    STAGE_A(1, 1, 0);
    VM2(); BAR();

#pragma unroll 1
    for (int jj = 0; jj < 8; ++jj) {
        KTILE(0, 2 * jj);
        KTILE(1, 2 * jj + 1);
    }

    // ---- epilogue: scatter into q (scaled by 0.125*log2e) / k / vT, per 16-col frag
    const int mrow = (m0 & 2047) + wr * 128 + g * 4;   // + mi*16 + r
    const int bb16 = (m0 >> 11) * 16;
#pragma unroll
    for (int ni = 0; ni < 3; ++ni) {
        const int nfr = n0 + wc * 48 + ni * 16;        // frag base col (mult of 16)
        const int s = nfr >> 10;
        const int rem = nfr & 1023;
        const int headg = bb16 + (rem >> 6);
        const int d0 = rem & 63;
        const float bv = bias[nfr + li];
        if (s == 2) {
#pragma unroll
            for (int mi = 0; mi < 8; ++mi) {
                bf16x4 st;
#pragma unroll
                for (int r = 0; r < 4; ++r) st[r] = (__bf16)(acc[mi][ni][r] + bv);
                *reinterpret_cast<bf16x4*>(
                    &vtg[((size_t)(headg * 64) + d0 + li) * 2048 + mrow + mi * 16]) = st;
            }
        } else {
            __bf16* og = (s == 0) ? qg : kg;
            const float sc = (s == 0) ? 0.18033688f : 1.0f;   // 0.125 * log2(e)
#pragma unroll
            for (int mi = 0; mi < 8; ++mi) {
#pragma unroll
                for (int r = 0; r < 4; ++r) {
                    og[((size_t)headg * 2048 + mrow + mi * 16 + r) * 64 + d0 + li] =
                        (__bf16)((acc[mi][ni][r] + bv) * sc);
                }
            }
        }
    }
#undef KTILE
#undef MFMA_QUAD
#undef READ_A
#undef READ_B
#undef STAGE_A
#undef STAGE_B
}

// ------- proj GEMM: 128x64 tile, BK=64, 3-buffer counted-vmcnt (distance-1) -------
__global__ __launch_bounds__(256) void gemm_proj_k(
    const __bf16* __restrict__ A, const __bf16* __restrict__ Bm,
    const float* __restrict__ bias, float* __restrict__ outf)
{
    __shared__ __align__(16) __bf16 As[3][8192];   // [buf][128 r x 64], XOR-swz slots
    __shared__ __align__(16) __bf16 Bs[3][4096];   // [buf][64 r x 64], XOR-swz
    const int t = threadIdx.x;
    const int lane = t & 63, w = t >> 6;
    const int li = lane & 15, g = lane >> 4;
    const int wr = w >> 1, wc = w & 1;
    const int sw7 = li & 7;
    const int bid = (blockIdx.x & 7) * 64 + (blockIdx.x >> 3);
    const int m0 = (bid >> 4) << 7;   // 32 m-tiles
    const int n0 = (bid & 15) << 6;   // 16 n-tiles

#define PSTAGE(BUF, KT) do {                                                      \
    _Pragma("unroll")                                                             \
    for (int c_ = 0; c_ < 4; ++c_) {                                              \
        const int row_ = c_ * 32 + (t >> 3);                                      \
        async_copy16(A + (size_t)(m0 + row_) * 1024 + ((KT) << 6)                 \
                       + (((t & 7) ^ (row_ & 7)) << 3),                           \
                     &As[BUF][0] + c_ * 2048 + t * 8);                            \
    }                                                                             \
    _Pragma("unroll")                                                             \
    for (int c_ = 0; c_ < 2; ++c_) {                                              \
        const int row_ = c_ * 32 + (t >> 3);                                      \
        async_copy16(Bm + (size_t)(n0 + row_) * 1024 + ((KT) << 6)                \
                       + (((t & 7) ^ (row_ & 7)) << 3),                           \
                     &Bs[BUF][0] + c_ * 2048 + t * 8);                            \
    }                                                                             \
} while (0)

    f32x4 acc[4][2] = {};

    PSTAGE(0, 0);
    int cur = 0;
    for (int kt = 0; kt < 16; ++kt) {
        int nxt = cur + 1; if (nxt == 3) nxt = 0;
        if (kt < 15) {
            PSTAGE(nxt, kt + 1);
            VM6();
        } else {
            asm volatile("s_waitcnt vmcnt(0)" ::: "memory");
        }
        __builtin_amdgcn_sched_barrier(0);
        __builtin_amdgcn_s_barrier();
        __builtin_amdgcn_sched_barrier(0);

        bf16x8 af[4][2], bf[2][2];
#pragma unroll
        for (int mi = 0; mi < 4; ++mi) {
            const int ra = wr * 64 + mi * 16 + li;
#pragma unroll
            for (int kk = 0; kk < 2; ++kk)
                af[mi][kk] = *reinterpret_cast<const bf16x8*>(
                    (char*)&As[cur][0] + ra * 128 + (((kk * 4 + g) ^ sw7) << 4));
        }
#pragma unroll
        for (int ni = 0; ni < 2; ++ni) {
            const int rb = wc * 32 + ni * 16 + li;
#pragma unroll
            for (int kk = 0; kk < 2; ++kk)
                bf[ni][kk] = *reinterpret_cast<const bf16x8*>(
                    (char*)&Bs[cur][0] + rb * 128 + (((kk * 4 + g) ^ sw7) << 4));
        }
        __builtin_amdgcn_s_setprio(1);
#pragma unroll
        for (int mi = 0; mi < 4; ++mi)
#pragma unroll
            for (int ni = 0; ni < 2; ++ni) {
                f32x4 c_ = acc[mi][ni];
                c_ = MFMA16(af[mi][0], bf[ni][0], c_);
                c_ = MFMA16(af[mi][1], bf[ni][1], c_);
                acc[mi][ni] = c_;
            }
        __builtin_amdgcn_s_setprio(0);
        cur = nxt;
    }
#undef PSTAGE

#pragma unroll
    for (int mi = 0; mi < 4; ++mi) {
#pragma unroll
        for (int ni = 0; ni < 2; ++ni) {
            const int n = n0 + wc * 32 + ni * 16 + li;
            const float bv = bias[n];
#pragma unroll
            for (int r = 0; r < 4; ++r) {
                const int m = m0 + wr * 64 + mi * 16 + g * 4 + r;
                outf[(size_t)m * 1024 + n] = acc[mi][ni][r] + bv;
            }
        }
    }
}

// ------- flash attention, causal: 8 waves x 16q, 2-buffer issue-early/wait-late ---
// T3 minimum-2-phase recipe: STAGE(kt+1) -> compute(kt) -> vmcnt(0) -> s_barrier.
// The drain sits AFTER the compute, so the 2 stage loads have the whole (~600cy)
// compute to land (r8's regression was draining immediately after issue; r12's
// quad-buffer hid it by distance-2 at 80KB LDS). WAR-safe: iteration kt writes
// buf[cur^1], whose readers (iteration kt-1) completed before the barrier ending
// kt-1. LDS = 2*16KB K/V + 16KB Ps = 48KB -> 3 blocks/CU (24 waves/CU nominal).
// q:[BH,2048,64] (scale*log2e prefolded), k:[BH,2048,64], vT:[BH,64,2048] bf16.
__global__ __launch_bounds__(512) void attn_k(
    const __bf16* __restrict__ qg, const __bf16* __restrict__ kg,
    const __bf16* __restrict__ vtg, const int* __restrict__ mflag,
    const int* __restrict__ mask, __bf16* __restrict__ ao)
{
    __shared__ __align__(16) __bf16 Ks[2][4096];   // [64 keys][64 d], 16B-slot XOR-swz
    __shared__ __align__(16) __bf16 Vs[2][4096];   // [64 d][64 keys], XOR-swz
    __shared__ __align__(16) __bf16 Ps[8][1024];   // per-wave P [16 q][64 keys], XOR-swz
    const int t = threadIdx.x;
    const int w = t >> 6, lane = t & 63;
    const int li = lane & 15, g = lane >> 4;
    const int xcd = blockIdx.x & 7;
    const int idx = blockIdx.x >> 3;          // 0..63
    const int hg  = xcd * 4 + (idx & 3);      // 0..31
    const int q_  = idx >> 2;                 // 0..15
    const int band = (q_ < 8) ? (15 - q_) : (q_ - 8);
    const int bI = hg >> 4, hI = hg & 15;
    const int iq = band * 128 + w * 16 + li;  // this lane's query row
    const int mydiag = 2 * band + (w >> 2);   // this wave's last 64-key tile
    const int ktmax = 2 * band + 1;           // block's last staged tile (>=1)
    const int rowt = 2 * band + (w >> 2);     // wave's 64-row mask tile
    const size_t hoff = (size_t)hg * (2048 * 64);
    const __bf16* qh = qg + hoff;
    const __bf16* kh = kg + hoff;
    const __bf16* vh = vtg + hoff;
    char* pw = (char*)&Ps[w][0];
    const int sw7 = li & 7;

    // Q B-operand frags: qf[half] = Q[iq][32*half + 8g + j]
    bf16x8 qf[2];
#pragma unroll
    for (int half = 0; half < 2; ++half)
        qf[half] = *reinterpret_cast<const bf16x8*>(&qh[(size_t)iq * 64 + half * 32 + g * 8]);

    f32x4 o[4] = {};                          // O[d=16df+4g+r][q=li]
    float mrun = -1e30f, lrun = 0.0f;         // lrun = per-lane partial (own keys)

    // stage one 64-key tile into buffer BUF: K 8KB + V 8KB, 512 thr x 16B each
#define STAGE(BUF, KT) do {                                                       \
    const int p_ = t * 16;                                                        \
    const int row_ = p_ >> 7, sl_ = (p_ >> 4) & 7;                                \
    const int gc_ = (sl_ ^ (row_ & 7)) << 3;                                      \
    async_copy16(kh + (size_t)(((KT) << 6) + row_) * 64 + gc_,                    \
                 (__bf16*)((char*)(&Ks[0][0]) + (BUF) * 8192 + p_));              \
    async_copy16(vh + (size_t)row_ * 2048 + ((KT) << 6) + gc_,                    \
                 (__bf16*)((char*)(&Vs[0][0]) + (BUF) * 8192 + p_));              \
} while (0)

    // prologue: tile 0 staged, drained, synced.
    STAGE(0, 0);
    asm volatile("s_waitcnt vmcnt(0)" ::: "memory");
    __builtin_amdgcn_s_barrier();

    int cur = 0;
    for (int kt = 0; kt <= ktmax; ++kt) {
        // issue-early: next tile into the other buffer (WAR-safe post-barrier)
        if (kt < ktmax) STAGE(cur ^ 1, kt + 1);
        __builtin_amdgcn_sched_barrier(0);
        if (kt <= mydiag) {
            const char* kb = (char*)&Ks[0][0] + cur * 8192;
            const char* vb = (char*)&Vs[0][0] + cur * 8192;
            // ---- S^T = K Q^T : s[kb_][r] = S[key = 64kt+16kb_+4g+r][q = li]
            f32x4 s[4] = {};
            __builtin_amdgcn_s_setprio(1);
#pragma unroll
            for (int kb_ = 0; kb_ < 4; ++kb_) {
                const int row = kb_ * 16 + li;
#pragma unroll
                for (int half = 0; half < 2; ++half) {
                    bf16x8 kf = *reinterpret_cast<const bf16x8*>(
                        kb + row * 128 + (((half * 4 + g) ^ sw7) << 4));
                    s[kb_] = MFMA16(kf, qf[half], s[kb_]);
                }
            }
            __builtin_amdgcn_s_setprio(0);
            // ---- causal / padding mask (diag tile only; pad path never taken here)
            const bool pflag = (mflag[(bI * 32 + rowt) * 32 + kt] == 0);
            if (pflag || kt == mydiag) {
                const int jb = kt * 64;
#pragma unroll
                for (int kb_ = 0; kb_ < 4; ++kb_)
#pragma unroll
                    for (int r = 0; r < 4; ++r) {
                        const int j0 = jb + kb_ * 16 + 4 * g + r;
                        float v0 = s[kb_][r];
                        if (j0 > iq ||
                            (pflag && mask[((size_t)(bI * 2048 + iq)) * 2048 + j0] == 0))
                            v0 = -1e30f;
                        s[kb_][r] = v0;
                    }
            }
            // ---- online softmax, exp2 domain, defer-max (THR=8)
            float mt = fmaxf(fmaxf(s[0][0], s[0][1]), fmaxf(s[0][2], s[0][3]));
#pragma unroll
            for (int kb_ = 1; kb_ < 4; ++kb_)
                mt = fmaxf(mt, fmaxf(fmaxf(s[kb_][0], s[kb_][1]),
                                     fmaxf(s[kb_][2], s[kb_][3])));
            mt = fmaxf(mt, __shfl_xor(mt, 16));
            mt = fmaxf(mt, __shfl_xor(mt, 32));
            if (!__all(mt <= mrun + 8.0f)) {
                const float mn = fmaxf(mrun, mt);
                const float alpha = exp2f(mrun - mn);
#pragma unroll
                for (int df = 0; df < 4; ++df)
#pragma unroll
                    for (int r = 0; r < 4; ++r) o[df][r] *= alpha;
                lrun *= alpha;
                mrun = mn;
            }
#pragma unroll
            for (int kb_ = 0; kb_ < 4; ++kb_)
#pragma unroll
                for (int r = 0; r < 4; ++r) {
                    const float p = exp2f(s[kb_][r] - mrun);
                    s[kb_][r] = p;
                    lrun += p;
                }
            // ---- P -> per-wave LDS (swizzled), lands in PV B-operand layout
#pragma unroll
            for (int kb_ = 0; kb_ < 4; ++kb_) {
                const unsigned lo = packbf(s[kb_][0], s[kb_][1]);
                const unsigned hi = packbf(s[kb_][2], s[kb_][3]);
                *reinterpret_cast<uint2*>(
                    pw + li * 128 + (((2 * kb_ + (g >> 1)) ^ sw7) << 4) + ((g & 1) << 3)) =
                    make_uint2(lo, hi);
            }
            bf16x8 pb[2];
#pragma unroll
            for (int ks = 0; ks < 2; ++ks)
                pb[ks] = *reinterpret_cast<const bf16x8*>(
                    pw + li * 128 + (((4 * ks + g) ^ sw7) << 4));
            // ---- O += V^T P : A = Vt rows (d), 8 MFMA16
            __builtin_amdgcn_s_setprio(1);
#pragma unroll
            for (int df = 0; df < 4; ++df) {
                const int vrow = df * 16 + li;
#pragma unroll
                for (int ks = 0; ks < 2; ++ks) {
                    bf16x8 vf = *reinterpret_cast<const bf16x8*>(
                        vb + vrow * 128 + (((4 * ks + g) ^ sw7) << 4));
                    o[df] = MFMA16(vf, pb[ks], o[df]);
                }
            }
            __builtin_amdgcn_s_setprio(0);
        }
        // wait-late: drain this iteration's stage loads (hidden under compute)
        __builtin_amdgcn_sched_barrier(0);
        asm volatile("s_waitcnt vmcnt(0)" ::: "memory");
        __builtin_amdgcn_s_barrier();
        __builtin_amdgcn_sched_barrier(0);
        cur ^= 1;
    }
#undef STAGE

    // ---- epilogue: finish lrun reduction, normalize, write
    lrun += __shfl_xor(lrun, 16);
    lrun += __shfl_xor(lrun, 32);
    const float inv = 1.0f / lrun;
    __bf16* aor = ao + ((size_t)(bI * 2048 + iq)) * 1024 + hI * 64 + g * 4;
#pragma unroll
    for (int df = 0; df < 4; ++df) {
        bf16x4 st;
#pragma unroll
        for (int r = 0; r < 4; ++r) st[r] = (__bf16)(o[df][r] * inv);
        *reinterpret_cast<bf16x4*>(&aor[df * 16]) = st;
    }
}

// ------------------------------- launch -----------------------------------------
extern "C" void kernel_launch(void* const* d_in, const int* in_sizes, int n_in,
                              void* d_out, int out_size, void* d_ws, size_t ws_size,
                              hipStream_t stream)
{
    const float* x      = (const float*)d_in[0];
    const int*   mask   = (const int*)d_in[1];
    const float* qkv_w  = (const float*)d_in[2];
    const float* qkv_b  = (const float*)d_in[3];
    const float* proj_w = (const float*)d_in[4];
    const float* proj_b = (const float*)d_in[5];
    float* out = (float*)d_out;

    char* ws = (char*)d_ws;
    __bf16* xb    = (__bf16*)(ws + 0);          // 4096x1024        8 MB
    __bf16* wqkv  = (__bf16*)(ws + 8388608);    // 3072x1024        6 MB
    __bf16* wproj = (__bf16*)(ws + 14680064);   // 1024x1024        2 MB
    __bf16* qg    = (__bf16*)(ws + 16777216);   // [32,2048,64]     8 MB
    __bf16* kg    = (__bf16*)(ws + 25165824);   // [32,2048,64]     8 MB
    __bf16* vtg   = (__bf16*)(ws + 33554432);   // [32,64,2048]     8 MB
    __bf16* ao    = (__bf16*)(ws + 41943040);   // 4096x1024        8 MB
    int*    mflag = (int*)(ws + 50331648);      // [2,32,32]        4 KB

    prep_k<<<10240, 256, 0, stream>>>(x, xb, qkv_w, wqkv, proj_w, wproj, mask, mflag);
    gemm_qkv8_k<<<256, 512, 0, stream>>>(xb, wqkv, qkv_b, qg, kg, vtg);
    attn_k<<<512, 512, 0, stream>>>(qg, kg, vtg, mflag, mask, ao);
    gemm_proj_k<<<512, 256, 0, stream>>>(ao, wproj, proj_b, out);
}

// Round 18
// 116.618 us; speedup vs baseline: 1.0418x; 1.0418x over previous
//
#include <hip/hip_runtime.h>
#include <hip/hip_bf16.h>

// UnifiedAttention: x->QKV gemm -> causal MHA (H=16,D=64) -> proj gemm
// B=2, N=2048, C=1024. bf16 MFMA with fp32 accum throughout.

typedef __bf16 bf16x8 __attribute__((ext_vector_type(8)));
typedef __bf16 bf16x4 __attribute__((ext_vector_type(4)));
typedef __bf16 bf16x2 __attribute__((ext_vector_type(2)));
typedef float  f32x4  __attribute__((ext_vector_type(4)));
typedef float  f32x16 __attribute__((ext_vector_type(16)));
typedef int    i32x4  __attribute__((ext_vector_type(4)));

#define MFMA16(a, b, c) __builtin_amdgcn_mfma_f32_16x16x32_bf16((a), (b), (c), 0, 0, 0)

__device__ __forceinline__ void async_copy16(const __bf16* g, __bf16* l) {
    __builtin_amdgcn_global_load_lds(
        (const __attribute__((address_space(1))) void*)g,
        (__attribute__((address_space(3))) void*)l,
        16, 0, 0);
}

__device__ __forceinline__ unsigned packbf(float a, float b) {
    union { bf16x2 v; unsigned u; } un;
    un.v[0] = (__bf16)a; un.v[1] = (__bf16)b;
    return un.u;
}

// -------- merged prep: fp32->bf16 conversions (blocks 0..8191) + mask reduce ------
__global__ void prep_k(const float* __restrict__ x, __bf16* __restrict__ xb,
                       const float* __restrict__ qkvw, __bf16* __restrict__ wqkv,
                       const float* __restrict__ projw, __bf16* __restrict__ wproj,
                       const int* __restrict__ mask, int* __restrict__ mflag)
{
    if (blockIdx.x < 8192) {
        const int i = blockIdx.x * 256 + threadIdx.x;   // quad index
        const float* src; __bf16* dst; int j;
        if (i < 1048576)            { src = x;     dst = xb;    j = i; }
        else if (i < 1835008)       { src = qkvw;  dst = wqkv;  j = i - 1048576; }
        else                        { src = projw; dst = wproj; j = i - 1835008; }
        float4 v = reinterpret_cast<const float4*>(src)[j];
        bf16x4 o;
        o[0] = (__bf16)v.x; o[1] = (__bf16)v.y; o[2] = (__bf16)v.z; o[3] = (__bf16)v.w;
        reinterpret_cast<bf16x4*>(dst)[j] = o;
    } else {
        __shared__ int ok;
        const int t = threadIdx.x;
        if (t == 0) ok = 1;
        __syncthreads();
        const int bb = blockIdx.x - 8192;
        const int jt = bb & 31;
        const int it = (bb >> 5) & 31;
        const int b  = bb >> 10;
        bool all1 = true;
#pragma unroll
        for (int c = 0; c < 4; ++c) {
            const int row = c * 16 + (t >> 4);
            const int col = (t & 15) * 4;
            const int4 v = *reinterpret_cast<const int4*>(
                &mask[((size_t)(b * 2048 + it * 64 + row)) * 2048 + jt * 64 + col]);
            all1 = all1 && v.x && v.y && v.z && v.w;
        }
        if (!all1) ok = 0;
        __syncthreads();
        if (t == 0) mflag[(b * 32 + it) * 32 + jt] = ok;
    }
}

// ====== 6-phase 256x192 QKV GEMM (T1+T2+T3+T4+T5), K=1024, grid 256 = 1/CU ======
#define BAR() asm volatile("s_barrier" ::: "memory")
#define VM2() asm volatile("s_waitcnt vmcnt(2)" ::: "memory")
#define VM6() asm volatile("s_waitcnt vmcnt(6)" ::: "memory")

__global__ __launch_bounds__(512, 2) void gemm_qkv8_k(
    const __bf16* __restrict__ A, const __bf16* __restrict__ Bm,
    const float* __restrict__ bias,
    __bf16* __restrict__ qg, __bf16* __restrict__ kg, __bf16* __restrict__ vtg)
{
    __shared__ __align__(16) __bf16 As[2][16384];   // [buf][256 rows x 64]
    __shared__ __align__(16) __bf16 Bs[2][12288];   // [buf][192 rows x 64]

    const int t = threadIdx.x;
    const int lane = t & 63;
    const int w = t >> 6;
    const int wr = w >> 2, wc = w & 3;
    const int li = lane & 15, g = lane >> 4;

    // XCD-aware bijective swizzle (grid=256, 256%8==0, 32 blocks per XCD)
    const int bid = (blockIdx.x & 7) * 32 + (blockIdx.x >> 3);
    const int m0 = (bid >> 4) << 8;     // 16 m-tiles of 256
    const int n0 = (bid & 15) * 192;    // 16 n-tiles of 192

    const int srow = t >> 3;            // 0..63
    const int scol = ((t & 7) ^ (srow & 7)) << 3;
    const __bf16* pA = A  + (size_t)(m0 + srow) * 1024 + scol;
    const __bf16* pB = Bm + (size_t)(n0 + srow) * 1024 + scol;
    __bf16* dA = &As[0][0] + t * 8;
    __bf16* dB = &Bs[0][0] + t * 8;

#define STAGE_A(BB, T, HH) do {                                                   \
    const size_t ro_ = (size_t)((HH) * 128) * 1024 + (size_t)(T) * 64;            \
    async_copy16(pA + ro_,         dA + (BB) * 16384 + (HH) * 8192);              \
    async_copy16(pA + ro_ + 65536, dA + (BB) * 16384 + (HH) * 8192 + 4096);       \
  } while (0)
#define STAGE_B(BB, T, HH) do {                                                   \
    const size_t ro_ = (size_t)((HH) * 64) * 1024 + (size_t)(T) * 64;             \
    async_copy16(pB + ro_, dB + (BB) * 12288 + (HH) * 4096);                      \
  } while (0)

    const int aoff0 = ((0 + g) ^ (li & 7)) << 3;
    const int aoff1 = ((4 + g) ^ (li & 7)) << 3;
    const int abase = (wr * 128 + li) * 64;
    const int bbase = (wc * 48 + li) * 64;

    f32x4 acc[8][3] = {};
    bf16x8 a[4][2], b[3][2];

#define READ_A(BB, MH) do { _Pragma("unroll")                                     \
    for (int mi2 = 0; mi2 < 4; ++mi2) {                                           \
      const __bf16* p_ = &As[BB][abase + ((MH) * 4 + mi2) * 1024];                \
      a[mi2][0] = *reinterpret_cast<const bf16x8*>(p_ + aoff0);                   \
      a[mi2][1] = *reinterpret_cast<const bf16x8*>(p_ + aoff1); } } while (0)
#define READ_B(BB, NH) do {                                                       \
      const __bf16* p_ = &Bs[BB][bbase + (NH) * 1024];                            \
      b[NH][0] = *reinterpret_cast<const bf16x8*>(p_ + aoff0);                    \
      b[NH][1] = *reinterpret_cast<const bf16x8*>(p_ + aoff1); } while (0)
#define MFMA_QUAD(MH, NH) do {                                                    \
    __builtin_amdgcn_s_setprio(1);                                                \
    _Pragma("unroll") for (int mi2 = 0; mi2 < 4; ++mi2) {                         \
      f32x4 c_ = acc[(MH) * 4 + mi2][NH];                                         \
      c_ = MFMA16(a[mi2][0], b[NH][0], c_);                                       \
      c_ = MFMA16(a[mi2][1], b[NH][1], c_);                                       \
      acc[(MH) * 4 + mi2][NH] = c_; }                                             \
    __builtin_amdgcn_s_setprio(0); } while (0)

#define KTILE(BB, T) do {                                                         \
    const int Tn_  = ((T) + 1 < 16) ? (T) + 1 : 15;                               \
    const int Tn2_ = ((T) + 2 < 16) ? (T) + 2 : 15;                               \
    STAGE_A((BB) ^ 1, Tn_, 1);                                                    \
    READ_A(BB, 0); READ_B(BB, 0);                                                 \
    BAR(); MFMA_QUAD(0, 0); BAR();                                                \
    STAGE_B((BB) ^ 1, Tn_, 0);                                                    \
    READ_B(BB, 1);                                                                \
    BAR(); MFMA_QUAD(0, 1); BAR();                                                \
    STAGE_B((BB) ^ 1, Tn_, 1);                                                    \
    READ_B(BB, 2);                                                                \
    BAR(); MFMA_QUAD(0, 2); BAR();                                                \
    STAGE_B((BB) ^ 1, Tn_, 2);                                                    \
    READ_A(BB, 1);                                                                \
    BAR(); MFMA_QUAD(1, 0); BAR();                                                \
    STAGE_A((BB), Tn2_, 0);                                                       \
    BAR(); MFMA_QUAD(1, 1); BAR();                                                \
    VM2();                                                                        \
    BAR(); MFMA_QUAD(1, 2); BAR();                                                \
  } while (0)

    STAGE_A(0, 0, 0); STAGE_A(0, 0, 1);
    STAGE_B(0, 0, 0); STAGE_B(0, 0, 1); STAGE_B(0, 0, 2);
    STAGE_A(1, 1, 0);
    VM2(); BAR();

#pragma unroll 1
    for (int jj = 0; jj < 8; ++jj) {
        KTILE(0, 2 * jj);
        KTILE(1, 2 * jj + 1);
    }

    // ---- epilogue: scatter into q (scaled by 0.125*log2e) / k / vT, per 16-col frag
    const int mrow = (m0 & 2047) + wr * 128 + g * 4;   // + mi*16 + r
    const int bb16 = (m0 >> 11) * 16;
#pragma unroll
    for (int ni = 0; ni < 3; ++ni) {
        const int nfr = n0 + wc * 48 + ni * 16;        // frag base col (mult of 16)
        const int s = nfr >> 10;
        const int rem = nfr & 1023;
        const int headg = bb16 + (rem >> 6);
        const int d0 = rem & 63;
        const float bv = bias[nfr + li];
        if (s == 2) {
#pragma unroll
            for (int mi = 0; mi < 8; ++mi) {
                bf16x4 st;
#pragma unroll
                for (int r = 0; r < 4; ++r) st[r] = (__bf16)(acc[mi][ni][r] + bv);
                *reinterpret_cast<bf16x4*>(
                    &vtg[((size_t)(headg * 64) + d0 + li) * 2048 + mrow + mi * 16]) = st;
            }
        } else {
            __bf16* og = (s == 0) ? qg : kg;
            const float sc = (s == 0) ? 0.18033688f : 1.0f;   // 0.125 * log2(e)
#pragma unroll
            for (int mi = 0; mi < 8; ++mi) {
#pragma unroll
                for (int r = 0; r < 4; ++r) {
                    og[((size_t)headg * 2048 + mrow + mi * 16 + r) * 64 + d0 + li] =
                        (__bf16)((acc[mi][ni][r] + bv) * sc);
                }
            }
        }
    }
#undef KTILE
#undef MFMA_QUAD
#undef READ_A
#undef READ_B
#undef STAGE_A
#undef STAGE_B
}

// ------- proj GEMM: 128x64 tile, BK=64, 3-buffer counted-vmcnt (distance-1) -------
__global__ __launch_bounds__(256) void gemm_proj_k(
    const __bf16* __restrict__ A, const __bf16* __restrict__ Bm,
    const float* __restrict__ bias, float* __restrict__ outf)
{
    __shared__ __align__(16) __bf16 As[3][8192];   // [buf][128 r x 64], XOR-swz slots
    __shared__ __align__(16) __bf16 Bs[3][4096];   // [buf][64 r x 64], XOR-swz
    const int t = threadIdx.x;
    const int lane = t & 63, w = t >> 6;
    const int li = lane & 15, g = lane >> 4;
    const int wr = w >> 1, wc = w & 1;
    const int sw7 = li & 7;
    const int bid = (blockIdx.x & 7) * 64 + (blockIdx.x >> 3);
    const int m0 = (bid >> 4) << 7;   // 32 m-tiles
    const int n0 = (bid & 15) << 6;   // 16 n-tiles

#define PSTAGE(BUF, KT) do {                                                      \
    _Pragma("unroll")                                                             \
    for (int c_ = 0; c_ < 4; ++c_) {                                              \
        const int row_ = c_ * 32 + (t >> 3);                                      \
        async_copy16(A + (size_t)(m0 + row_) * 1024 + ((KT) << 6)                 \
                       + (((t & 7) ^ (row_ & 7)) << 3),                           \
                     &As[BUF][0] + c_ * 2048 + t * 8);                            \
    }                                                                             \
    _Pragma("unroll")                                                             \
    for (int c_ = 0; c_ < 2; ++c_) {                                              \
        const int row_ = c_ * 32 + (t >> 3);                                      \
        async_copy16(Bm + (size_t)(n0 + row_) * 1024 + ((KT) << 6)                \
                       + (((t & 7) ^ (row_ & 7)) << 3),                           \
                     &Bs[BUF][0] + c_ * 2048 + t * 8);                            \
    }                                                                             \
} while (0)

    f32x4 acc[4][2] = {};

    PSTAGE(0, 0);
    int cur = 0;
    for (int kt = 0; kt < 16; ++kt) {
        int nxt = cur + 1; if (nxt == 3) nxt = 0;
        if (kt < 15) {
            PSTAGE(nxt, kt + 1);
            VM6();
        } else {
            asm volatile("s_waitcnt vmcnt(0)" ::: "memory");
        }
        __builtin_amdgcn_sched_barrier(0);
        __builtin_amdgcn_s_barrier();
        __builtin_amdgcn_sched_barrier(0);

        bf16x8 af[4][2], bf[2][2];
#pragma unroll
        for (int mi = 0; mi < 4; ++mi) {
            const int ra = wr * 64 + mi * 16 + li;
#pragma unroll
            for (int kk = 0; kk < 2; ++kk)
                af[mi][kk] = *reinterpret_cast<const bf16x8*>(
                    (char*)&As[cur][0] + ra * 128 + (((kk * 4 + g) ^ sw7) << 4));
        }
#pragma unroll
        for (int ni = 0; ni < 2; ++ni) {
            const int rb = wc * 32 + ni * 16 + li;
#pragma unroll
            for (int kk = 0; kk < 2; ++kk)
                bf[ni][kk] = *reinterpret_cast<const bf16x8*>(
                    (char*)&Bs[cur][0] + rb * 128 + (((kk * 4 + g) ^ sw7) << 4));
        }
        __builtin_amdgcn_s_setprio(1);
#pragma unroll
        for (int mi = 0; mi < 4; ++mi)
#pragma unroll
            for (int ni = 0; ni < 2; ++ni) {
                f32x4 c_ = acc[mi][ni];
                c_ = MFMA16(af[mi][0], bf[ni][0], c_);
                c_ = MFMA16(af[mi][1], bf[ni][1], c_);
                acc[mi][ni] = c_;
            }
        __builtin_amdgcn_s_setprio(0);
        cur = nxt;
    }
#undef PSTAGE

#pragma unroll
    for (int mi = 0; mi < 4; ++mi) {
#pragma unroll
        for (int ni = 0; ni < 2; ++ni) {
            const int n = n0 + wc * 32 + ni * 16 + li;
            const float bv = bias[n];
#pragma unroll
            for (int r = 0; r < 4; ++r) {
                const int m = m0 + wr * 64 + mi * 16 + g * 4 + r;
                outf[(size_t)m * 1024 + n] = acc[mi][ni][r] + bv;
            }
        }
    }
}

// ------- flash attention, causal: 4 waves x 16q (64-q band), 1024 blocks ---------
// Grid supplies 4 blocks/CU (LDS 40KB, VGPR ~44) -> 16 waves/CU resident.
// Issue-early/wait-late 2-buffer (r17 schedule, verified): STAGE(kt+1) ->
// compute(kt) -> vmcnt(0) -> s_barrier. All 4 waves share the same diagonal
// (mydiag == ktmax == band) so no per-wave predication. Per-wave math r12-exact.
// q:[BH,2048,64] (scale*log2e prefolded), k:[BH,2048,64], vT:[BH,64,2048] bf16.
__global__ __launch_bounds__(256) void attn_k(
    const __bf16* __restrict__ qg, const __bf16* __restrict__ kg,
    const __bf16* __restrict__ vtg, const int* __restrict__ mflag,
    const int* __restrict__ mask, __bf16* __restrict__ ao)
{
    __shared__ __align__(16) __bf16 Ks[2][4096];   // [64 keys][64 d], 16B-slot XOR-swz
    __shared__ __align__(16) __bf16 Vs[2][4096];   // [64 d][64 keys], XOR-swz
    __shared__ __align__(16) __bf16 Ps[4][1024];   // per-wave P [16 q][64 keys], XOR-swz
    const int t = threadIdx.x;
    const int w = t >> 6, lane = t & 63;
    const int li = lane & 15, g = lane >> 4;
    // block -> (head-group, 64q band): XCD x owns head-groups [4x,4x+4); heavy first
    const int xcd = blockIdx.x & 7;
    const int idx = blockIdx.x >> 3;          // 0..127
    const int hg  = xcd * 4 + (idx & 3);      // 0..31
    const int band = 31 - (idx >> 2);         // 0..31, heavy first
    const int bI = hg >> 4, hI = hg & 15;
    const int iq = band * 64 + w * 16 + li;   // this lane's query row
    const int ktmax = band;                   // uniform diag for all 4 waves
    const size_t hoff = (size_t)hg * (2048 * 64);
    const __bf16* qh = qg + hoff;
    const __bf16* kh = kg + hoff;
    const __bf16* vh = vtg + hoff;
    char* pw = (char*)&Ps[w][0];
    const int sw7 = li & 7;

    // Q B-operand frags: qf[half] = Q[iq][32*half + 8g + j]
    bf16x8 qf[2];
#pragma unroll
    for (int half = 0; half < 2; ++half)
        qf[half] = *reinterpret_cast<const bf16x8*>(&qh[(size_t)iq * 64 + half * 32 + g * 8]);

    f32x4 o[4] = {};                          // O[d=16df+4g+r][q=li]
    float mrun = -1e30f, lrun = 0.0f;         // lrun = per-lane partial (own keys)

    // stage one 64-key tile into buffer BUF: K 8KB + V 8KB, 256 thr x 4 loads
#define STAGE(BUF, KT) do {                                                       \
    _Pragma("unroll")                                                             \
    for (int c_ = 0; c_ < 2; ++c_) {                                              \
        const int p_ = c_ * 4096 + t * 16;                                        \
        const int row_ = p_ >> 7, sl_ = (p_ >> 4) & 7;                            \
        const int gc_ = (sl_ ^ (row_ & 7)) << 3;                                  \
        async_copy16(kh + (size_t)(((KT) << 6) + row_) * 64 + gc_,                \
                     (__bf16*)((char*)(&Ks[BUF][0]) + p_));                       \
        async_copy16(vh + (size_t)row_ * 2048 + ((KT) << 6) + gc_,                \
                     (__bf16*)((char*)(&Vs[BUF][0]) + p_));                       \
    }                                                                             \
} while (0)

    // prologue: tile 0 staged, drained, synced.
    STAGE(0, 0);
    asm volatile("s_waitcnt vmcnt(0)" ::: "memory");
    __builtin_amdgcn_s_barrier();

    int cur = 0;
    for (int kt = 0; kt <= ktmax; ++kt) {
        // issue-early: next tile into the other buffer (WAR-safe post-barrier)
        if (kt < ktmax) STAGE(cur ^ 1, kt + 1);
        __builtin_amdgcn_sched_barrier(0);
        {
            const char* kb = (char*)&Ks[cur][0];
            const char* vb = (char*)&Vs[cur][0];
            // ---- S^T = K Q^T : s[kb_][r] = S[key = 64kt+16kb_+4g+r][q = li]
            f32x4 s[4] = {};
            __builtin_amdgcn_s_setprio(1);
#pragma unroll
            for (int kb_ = 0; kb_ < 4; ++kb_) {
                const int row = kb_ * 16 + li;
#pragma unroll
                for (int half = 0; half < 2; ++half) {
                    bf16x8 kf = *reinterpret_cast<const bf16x8*>(
                        kb + row * 128 + (((half * 4 + g) ^ sw7) << 4));
                    s[kb_] = MFMA16(kf, qf[half], s[kb_]);
                }
            }
            __builtin_amdgcn_s_setprio(0);
            // ---- causal / padding mask (diag tile only; pad path never taken here)
            const bool pflag = (mflag[(bI * 32 + band) * 32 + kt] == 0);
            if (pflag || kt == ktmax) {
                const int jb = kt * 64;
#pragma unroll
                for (int kb_ = 0; kb_ < 4; ++kb_)
#pragma unroll
                    for (int r = 0; r < 4; ++r) {
                        const int j0 = jb + kb_ * 16 + 4 * g + r;
                        float v0 = s[kb_][r];
                        if (j0 > iq ||
                            (pflag && mask[((size_t)(bI * 2048 + iq)) * 2048 + j0] == 0))
                            v0 = -1e30f;
                        s[kb_][r] = v0;
                    }
            }
            // ---- online softmax, exp2 domain, defer-max (THR=8)
            float mt = fmaxf(fmaxf(s[0][0], s[0][1]), fmaxf(s[0][2], s[0][3]));
#pragma unroll
            for (int kb_ = 1; kb_ < 4; ++kb_)
                mt = fmaxf(mt, fmaxf(fmaxf(s[kb_][0], s[kb_][1]),
                                     fmaxf(s[kb_][2], s[kb_][3])));
            mt = fmaxf(mt, __shfl_xor(mt, 16));
            mt = fmaxf(mt, __shfl_xor(mt, 32));
            if (!__all(mt <= mrun + 8.0f)) {
                const float mn = fmaxf(mrun, mt);
                const float alpha = exp2f(mrun - mn);
#pragma unroll
                for (int df = 0; df < 4; ++df)
#pragma unroll
                    for (int r = 0; r < 4; ++r) o[df][r] *= alpha;
                lrun *= alpha;
                mrun = mn;
            }
#pragma unroll
            for (int kb_ = 0; kb_ < 4; ++kb_)
#pragma unroll
                for (int r = 0; r < 4; ++r) {
                    const float p = exp2f(s[kb_][r] - mrun);
                    s[kb_][r] = p;
                    lrun += p;
                }
            // ---- P -> per-wave LDS (swizzled), lands in PV B-operand layout
#pragma unroll
            for (int kb_ = 0; kb_ < 4; ++kb_) {
                const unsigned lo = packbf(s[kb_][0], s[kb_][1]);
                const unsigned hi = packbf(s[kb_][2], s[kb_][3]);
                *reinterpret_cast<uint2*>(
                    pw + li * 128 + (((2 * kb_ + (g >> 1)) ^ sw7) << 4) + ((g & 1) << 3)) =
                    make_uint2(lo, hi);
            }
            bf16x8 pb[2];
#pragma unroll
            for (int ks = 0; ks < 2; ++ks)
                pb[ks] = *reinterpret_cast<const bf16x8*>(
                    pw + li * 128 + (((4 * ks + g) ^ sw7) << 4));
            // ---- O += V^T P : A = Vt rows (d), 8 MFMA16
            __builtin_amdgcn_s_setprio(1);
#pragma unroll
            for (int df = 0; df < 4; ++df) {
                const int vrow = df * 16 + li;
#pragma unroll
                for (int ks = 0; ks < 2; ++ks) {
                    bf16x8 vf = *reinterpret_cast<const bf16x8*>(
                        vb + vrow * 128 + (((4 * ks + g) ^ sw7) << 4));
                    o[df] = MFMA16(vf, pb[ks], o[df]);
                }
            }
            __builtin_amdgcn_s_setprio(0);
        }
        // wait-late: drain this iteration's stage loads (hidden under compute)
        __builtin_amdgcn_sched_barrier(0);
        asm volatile("s_waitcnt vmcnt(0)" ::: "memory");
        __builtin_amdgcn_s_barrier();
        __builtin_amdgcn_sched_barrier(0);
        cur ^= 1;
    }
#undef STAGE

    // ---- epilogue: finish lrun reduction, normalize, write
    lrun += __shfl_xor(lrun, 16);
    lrun += __shfl_xor(lrun, 32);
    const float inv = 1.0f / lrun;
    __bf16* aor = ao + ((size_t)(bI * 2048 + iq)) * 1024 + hI * 64 + g * 4;
#pragma unroll
    for (int df = 0; df < 4; ++df) {
        bf16x4 st;
#pragma unroll
        for (int r = 0; r < 4; ++r) st[r] = (__bf16)(o[df][r] * inv);
        *reinterpret_cast<bf16x4*>(&aor[df * 16]) = st;
    }
}

// ------------------------------- launch -----------------------------------------
extern "C" void kernel_launch(void* const* d_in, const int* in_sizes, int n_in,
                              void* d_out, int out_size, void* d_ws, size_t ws_size,
                              hipStream_t stream)
{
    const float* x      = (const float*)d_in[0];
    const int*   mask   = (const int*)d_in[1];
    const float* qkv_w  = (const float*)d_in[2];
    const float* qkv_b  = (const float*)d_in[3];
    const float* proj_w = (const float*)d_in[4];
    const float* proj_b = (const float*)d_in[5];
    float* out = (float*)d_out;

    char* ws = (char*)d_ws;
    __bf16* xb    = (__bf16*)(ws + 0);          // 4096x1024        8 MB
    __bf16* wqkv  = (__bf16*)(ws + 8388608);    // 3072x1024        6 MB
    __bf16* wproj = (__bf16*)(ws + 14680064);   // 1024x1024        2 MB
    __bf16* qg    = (__bf16*)(ws + 16777216);   // [32,2048,64]     8 MB
    __bf16* kg    = (__bf16*)(ws + 25165824);   // [32,2048,64]     8 MB
    __bf16* vtg   = (__bf16*)(ws + 33554432);   // [32,64,2048]     8 MB
    __bf16* ao    = (__bf16*)(ws + 41943040);   // 4096x1024        8 MB
    int*    mflag = (int*)(ws + 50331648);      // [2,32,32]        4 KB

    prep_k<<<10240, 256, 0, stream>>>(x, xb, qkv_w, wqkv, proj_w, wproj, mask, mflag);
    gemm_qkv8_k<<<256, 512, 0, stream>>>(xb, wqkv, qkv_b, qg, kg, vtg);
    attn_k<<<1024, 256, 0, stream>>>(qg, kg, vtg, mflag, mask, ao);
    gemm_proj_k<<<512, 256, 0, stream>>>(ao, wproj, proj_b, out);
}